// Round 9
// baseline (190.792 us; speedup 1.0000x reference)
//
#include <hip/hip_runtime.h>
#include <math.h>

// ---------------------------------------------------------------------------
// HROMAttention: x(4,2048,512) -> QKV(+bias) -> RoPE -> MHA(8 heads, d=64)
//                -> proj(+bias). All GEMMs bf16 MFMA 16x16x32, fp32 accum.
// Round 10: attn cross-tile software pipeline — QK^T(t+1) MFMAs issued
//   BEFORE softmax(t) so their latency retires under the VALU chain
//   (R8 showed VALU count is not the critical path; the serial chain is).
//   One barrier/tile kept; staging split K-pre-barrier / V-post-barrier
//   per hazard analysis (Ks[cur] last read iter t-1; Vs[cur] read by PV(t)).
//   prep/qkv/proj unchanged from R8 (184.2 us best).
// ws layout (bytes):
//   [0)         xb     bf16 8192x512     8388608
//   [8388608)   wqb    bf16 1536x512     1572864
//   [9961472)   wpb    bf16  512x512      524288
//   [10485760)  cosT   f32  2048x32       262144
//   [10747904)  sinT   f32  2048x32       262144
//   [11010048)  Qb     bf16 (b,h,t,d)    8388608   (pre-scaled by 0.125*log2e)
//   [19398656)  Kb     bf16 (b,h,t,d)    8388608
//   [27787264)  Vtb    bf16 (b,h,d,t)    8388608
//   [36175872)  attnb  bf16 8192x512     8388608
//   [44564480)  maskE  f32  4x2048         32768   (mask * log2e)
// total 44597248 B (~42.5 MB) of d_ws
// ---------------------------------------------------------------------------

typedef __attribute__((ext_vector_type(8))) short bf16x8;
typedef __attribute__((ext_vector_type(4))) float floatx4;

#define LOG2E 1.44269504088896f
#define MAX3(a, b, c) fmaxf(fmaxf((a), (b)), (c))

__device__ __forceinline__ unsigned short f2bf(float f) {
  unsigned int u = __float_as_uint(f);
  u += 0x7fffu + ((u >> 16) & 1u);   // round-to-nearest-even
  return (unsigned short)(u >> 16);
}

// pack two f32 -> bf16x2 (low16 = a, high16 = b), RNE, single VALU inst
__device__ __forceinline__ unsigned int cvtpk_bf16(float a, float b) {
  unsigned int r;
  asm("v_cvt_pk_bf16_f32 %0, %1, %2" : "=v"(r) : "v"(a), "v"(b));
  return r;
}

__device__ __forceinline__ void gld_lds16(unsigned short* lds, const unsigned short* g) {
  __builtin_amdgcn_global_load_lds(
      (const __attribute__((address_space(1))) unsigned int*)g,
      (__attribute__((address_space(3))) unsigned int*)lds, 16, 0, 0);
}

// ---------------------------------------------------------------------------
// prep: bf16 conversions (8 elems/thread) + RoPE cos/sin table (fp64 trig)
//       + maskE = mask * log2e.
// conv threads [0,655360) | table [655360,720896) | maskE [720896,721920)
// ---------------------------------------------------------------------------
__global__ __launch_bounds__(256) void prep_kernel(
    const float* __restrict__ x, const float* __restrict__ wq, const float* __restrict__ wp,
    const float* __restrict__ mask,
    unsigned short* __restrict__ xb, unsigned short* __restrict__ wqb,
    unsigned short* __restrict__ wpb, float* __restrict__ cosT, float* __restrict__ sinT,
    float* __restrict__ maskE) {
  int i = blockIdx.x * 256 + threadIdx.x;
  if (i < 655360) {
    int base = i * 8;
    const float* src;
    unsigned short* dst;
    int j;
    if (base < 4194304)      { src = x;  dst = xb;  j = base; }
    else if (base < 4980736) { src = wq; dst = wqb; j = base - 4194304; }
    else                     { src = wp; dst = wpb; j = base - 4980736; }
    float4 a = *(const float4*)(src + j);
    float4 b = *(const float4*)(src + j + 4);
    uint4 r;
    r.x = cvtpk_bf16(a.x, a.y);
    r.y = cvtpk_bf16(a.z, a.w);
    r.z = cvtpk_bf16(b.x, b.y);
    r.w = cvtpk_bf16(b.z, b.w);
    *(uint4*)(dst + j) = r;
  } else if (i < 720896) {
    int j = i - 655360;
    int t = j >> 5, f = j & 31;
    double fr = (double)t * pow(10000.0, -(double)f / 32.0);
    cosT[j] = (float)cos(fr);
    sinT[j] = (float)sin(fr);
  } else if (i < 721920) {
    int j = (i - 720896) * 8;
    float4 a = *(const float4*)(mask + j);
    float4 b = *(const float4*)(mask + j + 4);
    a.x *= LOG2E; a.y *= LOG2E; a.z *= LOG2E; a.w *= LOG2E;
    b.x *= LOG2E; b.y *= LOG2E; b.z *= LOG2E; b.w *= LOG2E;
    *(float4*)(maskE + j) = a;
    *(float4*)(maskE + j + 4) = b;
  }
}

// ---------------------------------------------------------------------------
// QKV GEMM: xb(8192x512) @ wqb(1536x512)^T + bias, epilogue RoPE + scatter
// 128x128 tile, BK=32, 4 waves each 64x64. 2-phase dbuf pipeline.
// Q/K and V epilogues both re-tile through the dead 32 KB GEMM LDS for
// coalesced 16B stores.
// ---------------------------------------------------------------------------
__global__ __launch_bounds__(256) void qkv_kernel(
    const unsigned short* __restrict__ xb, const unsigned short* __restrict__ wqb,
    const float* __restrict__ qkv_b, const float* __restrict__ cosT,
    const float* __restrict__ sinT, unsigned short* __restrict__ Qb,
    unsigned short* __restrict__ Kb, unsigned short* __restrict__ Vtb) {
  // [buf][A=0/B=1][128*32] ; whole 32 KB reused as epilogue transpose buffer
  __shared__ __align__(16) unsigned short SM[2][2][128 * 32];
  const int tid = threadIdx.x;
  const int wave = tid >> 6, lane = tid & 63, ln = lane & 15, quad = lane >> 4;
  const int m0 = blockIdx.x * 128, n0 = blockIdx.y * 128;
  const int wr = (wave >> 1) * 64, wc = (wave & 1) * 64;

  floatx4 acc[4][4];
#pragma unroll
  for (int i = 0; i < 4; ++i)
#pragma unroll
    for (int j = 0; j < 4; ++j) acc[i][j] = (floatx4){0.f, 0.f, 0.f, 0.f};

  const int c0 = tid, c1 = tid + 256;
  const int ar0 = c0 >> 2, ak0 = (c0 & 3) * 8;
  const int ar1 = c1 >> 2, ak1 = (c1 & 3) * 8;

  // prologue: stage K-tile 0 into buffer 0
  gld_lds16(SM[0][0] + c0 * 8, xb + (size_t)(m0 + ar0) * 512 + ak0);
  gld_lds16(SM[0][0] + c1 * 8, xb + (size_t)(m0 + ar1) * 512 + ak1);
  gld_lds16(SM[0][1] + c0 * 8, wqb + (size_t)(n0 + ar0) * 512 + ak0);
  gld_lds16(SM[0][1] + c1 * 8, wqb + (size_t)(n0 + ar1) * 512 + ak1);
  __syncthreads();

  for (int kt = 0; kt < 16; ++kt) {
    const int cur = kt & 1;
    if (kt < 15) {
      const int kn = (kt + 1) * 32;
      gld_lds16(SM[cur ^ 1][0] + c0 * 8, xb + (size_t)(m0 + ar0) * 512 + kn + ak0);
      gld_lds16(SM[cur ^ 1][0] + c1 * 8, xb + (size_t)(m0 + ar1) * 512 + kn + ak1);
      gld_lds16(SM[cur ^ 1][1] + c0 * 8, wqb + (size_t)(n0 + ar0) * 512 + kn + ak0);
      gld_lds16(SM[cur ^ 1][1] + c1 * 8, wqb + (size_t)(n0 + ar1) * 512 + kn + ak1);
    }
    bf16x8 af[4], bfb[4];
#pragma unroll
    for (int mi = 0; mi < 4; ++mi)
      af[mi] = *(const bf16x8*)(SM[cur][0] + (wr + mi * 16 + ln) * 32 + quad * 8);
#pragma unroll
    for (int ni = 0; ni < 4; ++ni)
      bfb[ni] = *(const bf16x8*)(SM[cur][1] + (wc + ni * 16 + ln) * 32 + quad * 8);
#pragma unroll
    for (int mi = 0; mi < 4; ++mi)
#pragma unroll
      for (int ni = 0; ni < 4; ++ni)
        acc[mi][ni] = __builtin_amdgcn_mfma_f32_16x16x32_bf16(af[mi], bfb[ni], acc[mi][ni], 0, 0, 0);
    __syncthreads();
  }

  // epilogue: mat is block-uniform (512 % 128 == 0)
  const int colbase = n0 + wc;                    // multiple of 64
  const int mat = colbase >> 9;                   // 0=q 1=k 2=v
  float bias[4];
#pragma unroll
  for (int ni = 0; ni < 4; ++ni) bias[ni] = qkv_b[colbase + ni * 16 + ln];

  unsigned short* Ls = &SM[0][0][0];              // 32 KB scratch, GEMM tiles dead
  const int bidx = m0 >> 11, tl0 = m0 & 2047;     // block spans one batch
  const int h0 = (n0 & 511) >> 6;                 // first head in block

  if (mat == 2) {
    // V: Ls[c][r], c = local col (head*64+d), r = local t; phys granule swizzle
#pragma unroll
    for (int mi = 0; mi < 4; ++mi) {
      int r0 = wr + mi * 16 + quad * 4;            // 4 consecutive t
#pragma unroll
      for (int ni = 0; ni < 4; ++ni) {
        int c = wc + ni * 16 + ln;
        ushort4 pk;
        pk.x = f2bf(acc[mi][ni][0] + bias[ni]);
        pk.y = f2bf(acc[mi][ni][1] + bias[ni]);
        pk.z = f2bf(acc[mi][ni][2] + bias[ni]);
        pk.w = f2bf(acc[mi][ni][3] + bias[ni]);
        *(ushort4*)(Ls + c * 128 + (r0 ^ ((c & 7) << 3))) = pk;
      }
    }
    __syncthreads();
    // store: lanes cover t-contiguous 16B chunks of one (bh,d) row
    const int j2 = tid & 15, rid = tid >> 4;
#pragma unroll
    for (int it = 0; it < 8; ++it) {
      int c = it * 16 + rid;                       // 0..127
      int hh = c >> 6, dd = c & 63;
      uint4 v = *(const uint4*)(Ls + c * 128 + ((j2 * 8) ^ ((c & 7) << 3)));
      *(uint4*)(Vtb + ((size_t)(bidx * 8 + h0 + hh) * 64 + dd) * 2048 + tl0 + j2 * 8) = v;
    }
  } else {
    // Q/K: RoPE in-register -> Ls[r][c] (r = local t, c = local col), then
    // coalesced 16B stores along d.
    unsigned short* dst = (mat == 0) ? Qb : Kb;
    const float sc = (mat == 0) ? 0.125f * LOG2E : 1.0f;
#pragma unroll
    for (int mi = 0; mi < 4; ++mi) {
#pragma unroll
      for (int r = 0; r < 4; ++r) {
        int lr = wr + mi * 16 + quad * 4 + r;      // local t 0..127
        int t = tl0 + lr;
        const float* cr = cosT + t * 32;
        const float* sr = sinT + t * 32;
        int xr = (lr & 7) << 3;
#pragma unroll
        for (int ni = 0; ni < 2; ++ni) {
          int dlo = ni * 16 + ln;                  // 0..31 within head
          float cv = cr[dlo], sv = sr[dlo];
          float xlo = acc[mi][ni][r] + bias[ni];
          float xhi = acc[mi][ni + 2][r] + bias[ni + 2];
          Ls[lr * 128 + ((wc + dlo) ^ xr)]      = f2bf((xlo * cv - xhi * sv) * sc);
          Ls[lr * 128 + ((wc + dlo + 32) ^ xr)] = f2bf((xhi * cv + xlo * sv) * sc);
        }
      }
    }
    __syncthreads();
    // store: 8 lanes cover one 128B (bh,t) row; 8 rows per wave per inst
    const int jj = tid & 7, rowid = tid >> 3;      // jj = 16B chunk, rowid 0..31
#pragma unroll
    for (int it = 0; it < 8; ++it) {
      int hr = it * 32 + rowid;                    // 0..255 head-rows
      int rr = hr & 127, hh = hr >> 7;
      int c = hh * 64 + jj * 8;
      uint4 v = *(const uint4*)(Ls + rr * 128 + (c ^ ((rr & 7) << 3)));
      *(uint4*)(dst + ((size_t)(bidx * 8 + h0 + hh) * 2048 + tl0 + rr) * 64 + jj * 8) = v;
    }
  }
}

// ---------------------------------------------------------------------------
// Transposed flash attention, round 10: cross-tile pipelined.
//   block = 128 q x one (b,h); 8 waves x 16 q; K-tile = 64. S^T = K·Q^T.
//   Per iter: QK(t+1) issued FIRST (retires under softmax(t)'s VALU chain),
//   then softmax(t) + P-pack + PV(t), then stage K(t+2) [pre-barrier],
//   barrier, stage V(t+2) [post-barrier]. One barrier/tile.
//   XOR-swizzled LDS; cvt_pk; defer-rescale; maskE adds; max3 trees.
// ---------------------------------------------------------------------------
__global__ __launch_bounds__(512) void attn_kernel(
    const unsigned short* __restrict__ Qb, const unsigned short* __restrict__ Kb,
    const unsigned short* __restrict__ Vtb, const float* __restrict__ maskE,
    unsigned short* __restrict__ attnb) {
  __shared__ __align__(16) unsigned short Ks[2][64 * 64];  // (t_k, d) swizzled
  __shared__ __align__(16) unsigned short Vs[2][64 * 64];  // (d, t_k) swizzled
  __shared__ __align__(16) unsigned short Ps[128 * 64];    // (q, t_k) swizzled

  const int tid = threadIdx.x;
  const int wave = tid >> 6, lane = tid & 63, ln = lane & 15, quad = lane >> 4;
  const int swz = (ln & 7) << 3;                 // row-derived XOR for frag reads
  const int bh = blockIdx.y;
  const int b = bh >> 3, h = bh & 7;
  const int q0 = blockIdx.x * 128;
  const int wq = wave * 16;                      // wave's local q base

  const unsigned short* Qhead = Qb + (size_t)bh * 2048 * 64;
  const unsigned short* Khead = Kb + (size_t)bh * 2048 * 64;
  const unsigned short* Vhead = Vtb + (size_t)bh * 64 * 2048;

  bf16x8 qf[2];
#pragma unroll
  for (int ks = 0; ks < 2; ++ks)
    qf[ks] = *(const bf16x8*)(Qhead + (size_t)(q0 + wq + ln) * 64 + ks * 32 + quad * 8);

  floatx4 o[4];   // O^T: [d-tile], lane col = q
#pragma unroll
  for (int mi2 = 0; mi2 < 4; ++mi2) o[mi2] = (floatx4){0.f, 0.f, 0.f, 0.f};
  float mrun = -INFINITY;
  float lrun = 0.f;

  const int srow = tid >> 3;                     // 0..63
  const int scol = (tid & 7) * 8;                // shorts
  const int sdst = srow * 64 + (scol ^ ((srow & 7) << 3));

  // prologue: stage tiles 0 and 1
  {
    uint4 ka = *(const uint4*)(Khead + (size_t)srow * 64 + scol);
    uint4 va = *(const uint4*)(Vhead + (size_t)srow * 2048 + scol);
    uint4 kb2 = *(const uint4*)(Khead + (size_t)(64 + srow) * 64 + scol);
    uint4 vb2 = *(const uint4*)(Vhead + (size_t)srow * 2048 + 64 + scol);
    *(uint4*)(Ks[0] + sdst) = ka;
    *(uint4*)(Vs[0] + sdst) = va;
    *(uint4*)(Ks[1] + sdst) = kb2;
    *(uint4*)(Vs[1] + sdst) = vb2;
  }
  __syncthreads();

  // QK(0) from Ks[0]
  floatx4 sm[4];
#pragma unroll
  for (int mi = 0; mi < 4; ++mi) {
    bf16x8 kf0 = *(const bf16x8*)(Ks[0] + (mi * 16 + ln) * 64 + ((quad * 8) ^ swz));
    bf16x8 kf1 = *(const bf16x8*)(Ks[0] + (mi * 16 + ln) * 64 + ((32 + quad * 8) ^ swz));
    floatx4 a = (floatx4){0.f, 0.f, 0.f, 0.f};
    a = __builtin_amdgcn_mfma_f32_16x16x32_bf16(kf0, qf[0], a, 0, 0, 0);
    a = __builtin_amdgcn_mfma_f32_16x16x32_bf16(kf1, qf[1], a, 0, 0, 0);
    sm[mi] = a;
  }

  for (int kt = 0; kt < 32; ++kt) {
    const int cur = kt & 1;
    const int k0 = kt * 64;

    // QK(t+1) from the OTHER buffer — issued before softmax(t) so the MFMA
    // latency retires under the VALU chain below.
    floatx4 smn[4];
    if (kt < 31) {
#pragma unroll
      for (int mi = 0; mi < 4; ++mi) {
        bf16x8 kf0 = *(const bf16x8*)(Ks[cur ^ 1] + (mi * 16 + ln) * 64 + ((quad * 8) ^ swz));
        bf16x8 kf1 = *(const bf16x8*)(Ks[cur ^ 1] + (mi * 16 + ln) * 64 + ((32 + quad * 8) ^ swz));
        floatx4 a = (floatx4){0.f, 0.f, 0.f, 0.f};
        a = __builtin_amdgcn_mfma_f32_16x16x32_bf16(kf0, qf[0], a, 0, 0, 0);
        a = __builtin_amdgcn_mfma_f32_16x16x32_bf16(kf1, qf[1], a, 0, 0, 0);
        smn[mi] = a;
      }
    }
    // prefetch tile t+2 (consumed at the staging writes below)
    uint4 kpre, vpre;
    if (kt < 30) {
      kpre = *(const uint4*)(Khead + (size_t)(k0 + 128 + srow) * 64 + scol);
      vpre = *(const uint4*)(Vhead + (size_t)srow * 2048 + k0 + 128 + scol);
    }

    // softmax(t): maskE adds, max3 tree, defer-rescale, exp2, pairwise psum
#pragma unroll
    for (int mi = 0; mi < 4; ++mi) {
      float4 mv = *(const float4*)(maskE + b * 2048 + k0 + mi * 16 + quad * 4);
      sm[mi][0] += mv.x; sm[mi][1] += mv.y;
      sm[mi][2] += mv.z; sm[mi][3] += mv.w;
    }
    float t0 = MAX3(sm[0][0], sm[0][1], sm[0][2]);
    float t1 = MAX3(sm[0][3], sm[1][0], sm[1][1]);
    float t2 = MAX3(sm[1][2], sm[1][3], sm[2][0]);
    float t3 = MAX3(sm[2][1], sm[2][2], sm[2][3]);
    float t4 = MAX3(sm[3][0], sm[3][1], sm[3][2]);
    float vmax = fmaxf(MAX3(t0, t1, t2), MAX3(t3, t4, sm[3][3]));
    vmax = fmaxf(vmax, __shfl_xor(vmax, 16));
    vmax = fmaxf(vmax, __shfl_xor(vmax, 32));
    if (__any(vmax > mrun)) {
      float nm = fmaxf(mrun, vmax);
      float alpha = exp2f(mrun - nm);   // lanes w/o growth: exp2(0)=1
      mrun = nm;
      lrun *= alpha;
#pragma unroll
      for (int mi2 = 0; mi2 < 4; ++mi2) {
        o[mi2][0] *= alpha; o[mi2][1] *= alpha;
        o[mi2][2] *= alpha; o[mi2][3] *= alpha;
      }
    }
    float ps[4];
#pragma unroll
    for (int mi = 0; mi < 4; ++mi) {
      float p0 = exp2f(sm[mi][0] - mrun);
      float p1 = exp2f(sm[mi][1] - mrun);
      float p2 = exp2f(sm[mi][2] - mrun);
      float p3 = exp2f(sm[mi][3] - mrun);
      sm[mi][0] = p0; sm[mi][1] = p1; sm[mi][2] = p2; sm[mi][3] = p3;
      ps[mi] = (p0 + p1) + (p2 + p3);
    }
    float psum = (ps[0] + ps[1]) + (ps[2] + ps[3]);
    psum += __shfl_xor(psum, 16);
    psum += __shfl_xor(psum, 32);
    lrun += psum;

    // P^T -> LDS (q, t_k): per-wave rows, no barrier needed
#pragma unroll
    for (int mi = 0; mi < 4; ++mi) {
      uint2 pk;
      pk.x = cvtpk_bf16(sm[mi][0], sm[mi][1]);
      pk.y = cvtpk_bf16(sm[mi][2], sm[mi][3]);
      *(uint2*)(Ps + (wq + ln) * 64 + ((mi * 16 + quad * 4) ^ swz)) = pk;
    }
    // O^T += V^T·P from Vs[cur]
#pragma unroll
    for (int ks = 0; ks < 2; ++ks) {
      bf16x8 pb = *(const bf16x8*)(Ps + (wq + ln) * 64 + ((ks * 32 + quad * 8) ^ swz));
#pragma unroll
      for (int mi2 = 0; mi2 < 4; ++mi2) {
        bf16x8 vf = *(const bf16x8*)(Vs[cur] + (mi2 * 16 + ln) * 64 + ((ks * 32 + quad * 8) ^ swz));
        o[mi2] = __builtin_amdgcn_mfma_f32_16x16x32_bf16(vf, pb, o[mi2], 0, 0, 0);
      }
    }

    // stage tile t+2 into buf[cur]:
    //   K write PRE-barrier  (Ks[cur] last read by QK(t) at iter t-1)
    //   V write POST-barrier (Vs[cur] read by PV(t) above, fenced by barrier)
    if (kt < 30) *(uint4*)(Ks[cur] + sdst) = kpre;
    if (kt < 31) __syncthreads();
    if (kt < 30) *(uint4*)(Vs[cur] + sdst) = vpre;

#pragma unroll
    for (int mi = 0; mi < 4; ++mi) sm[mi] = smn[mi];
  }

  // epilogue: O^T lane owns q-col (1/l per-lane), 4 consecutive d per store
  {
    float inv = 1.f / lrun;
    int t = q0 + wq + ln;
    size_t base = ((size_t)b * 2048 + t) * 512 + h * 64;
#pragma unroll
    for (int mi2 = 0; mi2 < 4; ++mi2) {
      uint2 pk;
      pk.x = cvtpk_bf16(o[mi2][0] * inv, o[mi2][1] * inv);
      pk.y = cvtpk_bf16(o[mi2][2] * inv, o[mi2][3] * inv);
      *(uint2*)(attnb + base + mi2 * 16 + quad * 4) = pk;
    }
  }
}

// ---------------------------------------------------------------------------
// proj GEMM: attnb(8192x512) @ wpb(512x512)^T + bias -> out fp32
// 64x64 tile, 256 threads (4 waves x 32x32), 2-phase dbuf pipeline.
// Grid (128,8) = 1024 blocks -> 4 blocks/CU -> 16 waves/CU.
// ---------------------------------------------------------------------------
__global__ __launch_bounds__(256) void proj_kernel(
    const unsigned short* __restrict__ ab, const unsigned short* __restrict__ wpb,
    const float* __restrict__ proj_b, float* __restrict__ out) {
  __shared__ __align__(16) unsigned short As[2][64 * 32];
  __shared__ __align__(16) unsigned short Bs[2][64 * 32];
  const int tid = threadIdx.x;
  const int wave = tid >> 6, lane = tid & 63, ln = lane & 15, quad = lane >> 4;
  const int m0 = blockIdx.x * 64, n0 = blockIdx.y * 64;
  const int wr = (wave >> 1) * 32, wc = (wave & 1) * 32;

  floatx4 acc[2][2];
#pragma unroll
  for (int i = 0; i < 2; ++i)
#pragma unroll
    for (int j = 0; j < 2; ++j) acc[i][j] = (floatx4){0.f, 0.f, 0.f, 0.f};

  // 256 threads stage 256 x 16B chunks: one A chunk + one B chunk each
  const int ar = tid >> 2, ak = (tid & 3) * 8;

  gld_lds16(As[0] + tid * 8, ab + (size_t)(m0 + ar) * 512 + ak);
  gld_lds16(Bs[0] + tid * 8, wpb + (size_t)(n0 + ar) * 512 + ak);
  __syncthreads();

  for (int kt = 0; kt < 16; ++kt) {
    const int cur = kt & 1;
    if (kt < 15) {
      const int kn = (kt + 1) * 32;
      gld_lds16(As[cur ^ 1] + tid * 8, ab + (size_t)(m0 + ar) * 512 + kn + ak);
      gld_lds16(Bs[cur ^ 1] + tid * 8, wpb + (size_t)(n0 + ar) * 512 + kn + ak);
    }
    bf16x8 af[2], bfb[2];
#pragma unroll
    for (int mi = 0; mi < 2; ++mi)
      af[mi] = *(const bf16x8*)(As[cur] + (wr + mi * 16 + ln) * 32 + quad * 8);
#pragma unroll
    for (int ni = 0; ni < 2; ++ni)
      bfb[ni] = *(const bf16x8*)(Bs[cur] + (wc + ni * 16 + ln) * 32 + quad * 8);
#pragma unroll
    for (int mi = 0; mi < 2; ++mi)
#pragma unroll
      for (int ni = 0; ni < 2; ++ni)
        acc[mi][ni] = __builtin_amdgcn_mfma_f32_16x16x32_bf16(af[mi], bfb[ni], acc[mi][ni], 0, 0, 0);
    __syncthreads();
  }

#pragma unroll
  for (int mi = 0; mi < 2; ++mi)
#pragma unroll
    for (int ni = 0; ni < 2; ++ni) {
      int col = n0 + wc + ni * 16 + ln;
      float pb = proj_b[col];
#pragma unroll
      for (int r = 0; r < 4; ++r) {
        int row = m0 + wr + mi * 16 + quad * 4 + r;
        out[(size_t)row * 512 + col] = acc[mi][ni][r] + pb;
      }
    }
}

// ---------------------------------------------------------------------------
extern "C" void kernel_launch(void* const* d_in, const int* in_sizes, int n_in,
                              void* d_out, int out_size, void* d_ws, size_t ws_size,
                              hipStream_t stream) {
  const float* x      = (const float*)d_in[0];
  const float* mask   = (const float*)d_in[1];
  const float* qkv_w  = (const float*)d_in[2];
  const float* qkv_b  = (const float*)d_in[3];
  const float* proj_w = (const float*)d_in[4];
  const float* proj_b = (const float*)d_in[5];
  float* out = (float*)d_out;

  char* ws = (char*)d_ws;
  unsigned short* xb   = (unsigned short*)(ws);
  unsigned short* wqb  = (unsigned short*)(ws + 8388608);
  unsigned short* wpb  = (unsigned short*)(ws + 9961472);
  float* cosT          = (float*)(ws + 10485760);
  float* sinT          = (float*)(ws + 10747904);
  unsigned short* Qb   = (unsigned short*)(ws + 11010048);
  unsigned short* Kb   = (unsigned short*)(ws + 19398656);
  unsigned short* Vtb  = (unsigned short*)(ws + 27787264);
  unsigned short* attnb= (unsigned short*)(ws + 36175872);
  float* maskE         = (float*)(ws + 44564480);

  prep_kernel<<<2820, 256, 0, stream>>>(x, qkv_w, proj_w, mask, xb, wqb, wpb, cosT, sinT, maskE);
  dim3 g1(64, 12);
  qkv_kernel<<<g1, 256, 0, stream>>>(xb, wqb, qkv_b, cosT, sinT, Qb, Kb, Vtb);
  dim3 g2(16, 32);
  attn_kernel<<<g2, 512, 0, stream>>>(Qb, Kb, Vtb, maskE, attnb);
  dim3 g3(128, 8);
  proj_kernel<<<g3, 256, 0, stream>>>(attnb, wpb, proj_b, out);
}

// Round 10
// 183.062 us; speedup vs baseline: 1.0422x; 1.0422x over previous
//
#include <hip/hip_runtime.h>
#include <math.h>

// ---------------------------------------------------------------------------
// HROMAttention: x(4,2048,512) -> QKV(+bias) -> RoPE -> MHA(8 heads, d=64)
//                -> proj(+bias). All GEMMs bf16 MFMA 16x16x32, fp32 accum.
// Round 11: compose best-measured variant of each kernel (no new experiments).
//   attn: exact R5 single-barrier reg-prefetch dbuf (82.4 us measured best;
//         R8 diet -3us, R9 pipeline -6us, R6/R7 structural changes all lost).
//   qkv:  R7 epilogue LDS re-tile (coalesced stores).
//   proj: R8 64x64 tiles, grid (128,8) -> 4 blocks/CU.
//   prep: R5 (no maskE; attn takes raw mask, inline *log2e).
// ws layout (bytes):
//   [0)         xb     bf16 8192x512     8388608
//   [8388608)   wqb    bf16 1536x512     1572864
//   [9961472)   wpb    bf16  512x512      524288
//   [10485760)  cosT   f32  2048x32       262144
//   [10747904)  sinT   f32  2048x32       262144
//   [11010048)  Qb     bf16 (b,h,t,d)    8388608   (pre-scaled by 0.125*log2e)
//   [19398656)  Kb     bf16 (b,h,t,d)    8388608
//   [27787264)  Vtb    bf16 (b,h,d,t)    8388608
//   [36175872)  attnb  bf16 8192x512     8388608
// total 44564480 B (~42.5 MB) of d_ws
// ---------------------------------------------------------------------------

typedef __attribute__((ext_vector_type(8))) short bf16x8;
typedef __attribute__((ext_vector_type(4))) float floatx4;

#define LOG2E 1.44269504088896f

__device__ __forceinline__ unsigned short f2bf(float f) {
  unsigned int u = __float_as_uint(f);
  u += 0x7fffu + ((u >> 16) & 1u);   // round-to-nearest-even
  return (unsigned short)(u >> 16);
}

// pack two f32 -> bf16x2 (low16 = a, high16 = b), RNE, single VALU inst
__device__ __forceinline__ unsigned int cvtpk_bf16(float a, float b) {
  unsigned int r;
  asm("v_cvt_pk_bf16_f32 %0, %1, %2" : "=v"(r) : "v"(a), "v"(b));
  return r;
}

__device__ __forceinline__ void gld_lds16(unsigned short* lds, const unsigned short* g) {
  __builtin_amdgcn_global_load_lds(
      (const __attribute__((address_space(1))) unsigned int*)g,
      (__attribute__((address_space(3))) unsigned int*)lds, 16, 0, 0);
}

// ---------------------------------------------------------------------------
// prep: bf16 conversions (8 elems/thread) + RoPE cos/sin table (fp64 trig)
// f32 elements: x 4194304 | wq 786432 | wp 262144  (all /8) -> 655360 threads
// table: 65536 entries, 1/thread -> threads 655360..720895
// ---------------------------------------------------------------------------
__global__ __launch_bounds__(256) void prep_kernel(
    const float* __restrict__ x, const float* __restrict__ wq, const float* __restrict__ wp,
    unsigned short* __restrict__ xb, unsigned short* __restrict__ wqb,
    unsigned short* __restrict__ wpb, float* __restrict__ cosT, float* __restrict__ sinT) {
  int i = blockIdx.x * 256 + threadIdx.x;
  if (i < 655360) {
    int base = i * 8;
    const float* src;
    unsigned short* dst;
    int j;
    if (base < 4194304)      { src = x;  dst = xb;  j = base; }
    else if (base < 4980736) { src = wq; dst = wqb; j = base - 4194304; }
    else                     { src = wp; dst = wpb; j = base - 4980736; }
    float4 a = *(const float4*)(src + j);
    float4 b = *(const float4*)(src + j + 4);
    uint4 r;
    r.x = cvtpk_bf16(a.x, a.y);
    r.y = cvtpk_bf16(a.z, a.w);
    r.z = cvtpk_bf16(b.x, b.y);
    r.w = cvtpk_bf16(b.z, b.w);
    *(uint4*)(dst + j) = r;
  } else if (i < 720896) {
    int j = i - 655360;
    int t = j >> 5, f = j & 31;
    double fr = (double)t * pow(10000.0, -(double)f / 32.0);
    cosT[j] = (float)cos(fr);
    sinT[j] = (float)sin(fr);
  }
}

// ---------------------------------------------------------------------------
// QKV GEMM: xb(8192x512) @ wqb(1536x512)^T + bias, epilogue RoPE + scatter
// 128x128 tile, BK=32, 4 waves each 64x64. 2-phase dbuf pipeline.
// Q/K and V epilogues both re-tile through the dead 32 KB GEMM LDS for
// coalesced 16B stores.
// ---------------------------------------------------------------------------
__global__ __launch_bounds__(256) void qkv_kernel(
    const unsigned short* __restrict__ xb, const unsigned short* __restrict__ wqb,
    const float* __restrict__ qkv_b, const float* __restrict__ cosT,
    const float* __restrict__ sinT, unsigned short* __restrict__ Qb,
    unsigned short* __restrict__ Kb, unsigned short* __restrict__ Vtb) {
  // [buf][A=0/B=1][128*32] ; whole 32 KB reused as epilogue transpose buffer
  __shared__ __align__(16) unsigned short SM[2][2][128 * 32];
  const int tid = threadIdx.x;
  const int wave = tid >> 6, lane = tid & 63, ln = lane & 15, quad = lane >> 4;
  const int m0 = blockIdx.x * 128, n0 = blockIdx.y * 128;
  const int wr = (wave >> 1) * 64, wc = (wave & 1) * 64;

  floatx4 acc[4][4];
#pragma unroll
  for (int i = 0; i < 4; ++i)
#pragma unroll
    for (int j = 0; j < 4; ++j) acc[i][j] = (floatx4){0.f, 0.f, 0.f, 0.f};

  const int c0 = tid, c1 = tid + 256;
  const int ar0 = c0 >> 2, ak0 = (c0 & 3) * 8;
  const int ar1 = c1 >> 2, ak1 = (c1 & 3) * 8;

  // prologue: stage K-tile 0 into buffer 0
  gld_lds16(SM[0][0] + c0 * 8, xb + (size_t)(m0 + ar0) * 512 + ak0);
  gld_lds16(SM[0][0] + c1 * 8, xb + (size_t)(m0 + ar1) * 512 + ak1);
  gld_lds16(SM[0][1] + c0 * 8, wqb + (size_t)(n0 + ar0) * 512 + ak0);
  gld_lds16(SM[0][1] + c1 * 8, wqb + (size_t)(n0 + ar1) * 512 + ak1);
  __syncthreads();

  for (int kt = 0; kt < 16; ++kt) {
    const int cur = kt & 1;
    if (kt < 15) {
      const int kn = (kt + 1) * 32;
      gld_lds16(SM[cur ^ 1][0] + c0 * 8, xb + (size_t)(m0 + ar0) * 512 + kn + ak0);
      gld_lds16(SM[cur ^ 1][0] + c1 * 8, xb + (size_t)(m0 + ar1) * 512 + kn + ak1);
      gld_lds16(SM[cur ^ 1][1] + c0 * 8, wqb + (size_t)(n0 + ar0) * 512 + kn + ak0);
      gld_lds16(SM[cur ^ 1][1] + c1 * 8, wqb + (size_t)(n0 + ar1) * 512 + kn + ak1);
    }
    bf16x8 af[4], bfb[4];
#pragma unroll
    for (int mi = 0; mi < 4; ++mi)
      af[mi] = *(const bf16x8*)(SM[cur][0] + (wr + mi * 16 + ln) * 32 + quad * 8);
#pragma unroll
    for (int ni = 0; ni < 4; ++ni)
      bfb[ni] = *(const bf16x8*)(SM[cur][1] + (wc + ni * 16 + ln) * 32 + quad * 8);
#pragma unroll
    for (int mi = 0; mi < 4; ++mi)
#pragma unroll
      for (int ni = 0; ni < 4; ++ni)
        acc[mi][ni] = __builtin_amdgcn_mfma_f32_16x16x32_bf16(af[mi], bfb[ni], acc[mi][ni], 0, 0, 0);
    __syncthreads();
  }

  // epilogue: mat is block-uniform (512 % 128 == 0)
  const int colbase = n0 + wc;                    // multiple of 64
  const int mat = colbase >> 9;                   // 0=q 1=k 2=v
  float bias[4];
#pragma unroll
  for (int ni = 0; ni < 4; ++ni) bias[ni] = qkv_b[colbase + ni * 16 + ln];

  unsigned short* Ls = &SM[0][0][0];              // 32 KB scratch, GEMM tiles dead
  const int bidx = m0 >> 11, tl0 = m0 & 2047;     // block spans one batch
  const int h0 = (n0 & 511) >> 6;                 // first head in block

  if (mat == 2) {
    // V: Ls[c][r], c = local col (head*64+d), r = local t; phys granule swizzle
#pragma unroll
    for (int mi = 0; mi < 4; ++mi) {
      int r0 = wr + mi * 16 + quad * 4;            // 4 consecutive t
#pragma unroll
      for (int ni = 0; ni < 4; ++ni) {
        int c = wc + ni * 16 + ln;
        ushort4 pk;
        pk.x = f2bf(acc[mi][ni][0] + bias[ni]);
        pk.y = f2bf(acc[mi][ni][1] + bias[ni]);
        pk.z = f2bf(acc[mi][ni][2] + bias[ni]);
        pk.w = f2bf(acc[mi][ni][3] + bias[ni]);
        *(ushort4*)(Ls + c * 128 + (r0 ^ ((c & 7) << 3))) = pk;
      }
    }
    __syncthreads();
    // store: lanes cover t-contiguous 16B chunks of one (bh,d) row
    const int j2 = tid & 15, rid = tid >> 4;
#pragma unroll
    for (int it = 0; it < 8; ++it) {
      int c = it * 16 + rid;                       // 0..127
      int hh = c >> 6, dd = c & 63;
      uint4 v = *(const uint4*)(Ls + c * 128 + ((j2 * 8) ^ ((c & 7) << 3)));
      *(uint4*)(Vtb + ((size_t)(bidx * 8 + h0 + hh) * 64 + dd) * 2048 + tl0 + j2 * 8) = v;
    }
  } else {
    // Q/K: RoPE in-register -> Ls[r][c] (r = local t, c = local col), then
    // coalesced 16B stores along d.
    unsigned short* dst = (mat == 0) ? Qb : Kb;
    const float sc = (mat == 0) ? 0.125f * LOG2E : 1.0f;
#pragma unroll
    for (int mi = 0; mi < 4; ++mi) {
#pragma unroll
      for (int r = 0; r < 4; ++r) {
        int lr = wr + mi * 16 + quad * 4 + r;      // local t 0..127
        int t = tl0 + lr;
        const float* cr = cosT + t * 32;
        const float* sr = sinT + t * 32;
        int xr = (lr & 7) << 3;
#pragma unroll
        for (int ni = 0; ni < 2; ++ni) {
          int dlo = ni * 16 + ln;                  // 0..31 within head
          float cv = cr[dlo], sv = sr[dlo];
          float xlo = acc[mi][ni][r] + bias[ni];
          float xhi = acc[mi][ni + 2][r] + bias[ni + 2];
          Ls[lr * 128 + ((wc + dlo) ^ xr)]      = f2bf((xlo * cv - xhi * sv) * sc);
          Ls[lr * 128 + ((wc + dlo + 32) ^ xr)] = f2bf((xhi * cv + xlo * sv) * sc);
        }
      }
    }
    __syncthreads();
    // store: 8 lanes cover one 128B (bh,t) row; 8 rows per wave per inst
    const int jj = tid & 7, rowid = tid >> 3;      // jj = 16B chunk, rowid 0..31
#pragma unroll
    for (int it = 0; it < 8; ++it) {
      int hr = it * 32 + rowid;                    // 0..255 head-rows
      int rr = hr & 127, hh = hr >> 7;
      int c = hh * 64 + jj * 8;
      uint4 v = *(const uint4*)(Ls + rr * 128 + (c ^ ((rr & 7) << 3)));
      *(uint4*)(dst + ((size_t)(bidx * 8 + h0 + hh) * 2048 + tl0 + rr) * 64 + jj * 8) = v;
    }
  }
}

// ---------------------------------------------------------------------------
// Transposed flash attention (exact R5 structure, 82.4 us measured best):
//   block = 128 q x one (b,h); 8 waves x 16 q each; K-tile = 64.
//   S^T = K·Q^T; XOR-swizzled LDS; cvt_pk P-pack; defer-rescale.
//   Loop: prefetch regs(t+1) -> compute from buf[cur] -> write buf[cur^1]
//   -> ONE barrier per tile.
// ---------------------------------------------------------------------------
__global__ __launch_bounds__(512) void attn_kernel(
    const unsigned short* __restrict__ Qb, const unsigned short* __restrict__ Kb,
    const unsigned short* __restrict__ Vtb, const float* __restrict__ mask,
    unsigned short* __restrict__ attnb) {
  __shared__ __align__(16) unsigned short Ks[2][64 * 64];  // (t_k, d) swizzled
  __shared__ __align__(16) unsigned short Vs[2][64 * 64];  // (d, t_k) swizzled
  __shared__ __align__(16) unsigned short Ps[128 * 64];    // (q, t_k) swizzled

  const int tid = threadIdx.x;
  const int wave = tid >> 6, lane = tid & 63, ln = lane & 15, quad = lane >> 4;
  const int swz = (ln & 7) << 3;                 // row-derived XOR for frag reads
  const int bh = blockIdx.y;
  const int b = bh >> 3, h = bh & 7;
  const int q0 = blockIdx.x * 128;
  const int wq = wave * 16;                      // wave's local q base

  const unsigned short* Qhead = Qb + (size_t)bh * 2048 * 64;
  const unsigned short* Khead = Kb + (size_t)bh * 2048 * 64;
  const unsigned short* Vhead = Vtb + (size_t)bh * 64 * 2048;

  bf16x8 qf[2];
#pragma unroll
  for (int ks = 0; ks < 2; ++ks)
    qf[ks] = *(const bf16x8*)(Qhead + (size_t)(q0 + wq + ln) * 64 + ks * 32 + quad * 8);

  floatx4 o[4];   // O^T: [d-tile], lane col = q
#pragma unroll
  for (int mi2 = 0; mi2 < 4; ++mi2) o[mi2] = (floatx4){0.f, 0.f, 0.f, 0.f};
  float mrun = -INFINITY;
  float lrun = 0.f;

  const int srow = tid >> 3;                     // 0..63
  const int scol = (tid & 7) * 8;                // shorts
  const int sdst = srow * 64 + (scol ^ ((srow & 7) << 3));

  // prologue: tile 0 -> regs -> buf 0
  {
    uint4 k0v = *(const uint4*)(Khead + (size_t)srow * 64 + scol);
    uint4 v0v = *(const uint4*)(Vhead + (size_t)srow * 2048 + scol);
    *(uint4*)(Ks[0] + sdst) = k0v;
    *(uint4*)(Vs[0] + sdst) = v0v;
  }
  __syncthreads();

  for (int kt = 0; kt < 32; ++kt) {
    const int cur = kt & 1;
    const int k0 = kt * 64;
    uint4 kpre, vpre;
    if (kt < 31) {   // prefetch next tile; latency hidden by compute below
      kpre = *(const uint4*)(Khead + (size_t)(k0 + 64 + srow) * 64 + scol);
      vpre = *(const uint4*)(Vhead + (size_t)srow * 2048 + k0 + 64 + scol);
    }

    // S^T = K·Q^T : A=K-frag A[m=t_k][k=d], B=Q. C: row=t_k(quad*4+r), col=q(ln)
    floatx4 sm[4];
#pragma unroll
    for (int mi = 0; mi < 4; ++mi) {
      bf16x8 kf0 = *(const bf16x8*)(Ks[cur] + (mi * 16 + ln) * 64 + ((quad * 8) ^ swz));
      bf16x8 kf1 = *(const bf16x8*)(Ks[cur] + (mi * 16 + ln) * 64 + ((32 + quad * 8) ^ swz));
      floatx4 a = (floatx4){0.f, 0.f, 0.f, 0.f};
      a = __builtin_amdgcn_mfma_f32_16x16x32_bf16(kf0, qf[0], a, 0, 0, 0);
      a = __builtin_amdgcn_mfma_f32_16x16x32_bf16(kf1, qf[1], a, 0, 0, 0);
      sm[mi] = a;
    }
#pragma unroll
    for (int mi = 0; mi < 4; ++mi) {
      float4 mv = *(const float4*)(mask + b * 2048 + k0 + mi * 16 + quad * 4);
      sm[mi][0] += mv.x * LOG2E; sm[mi][1] += mv.y * LOG2E;
      sm[mi][2] += mv.z * LOG2E; sm[mi][3] += mv.w * LOG2E;
    }
    // online softmax: per lane one q-column -> 15 in-reg max + 2 shuffles
    float vmax = fmaxf(fmaxf(sm[0][0], sm[0][1]), fmaxf(sm[0][2], sm[0][3]));
#pragma unroll
    for (int mi = 1; mi < 4; ++mi)
      vmax = fmaxf(vmax, fmaxf(fmaxf(sm[mi][0], sm[mi][1]), fmaxf(sm[mi][2], sm[mi][3])));
    vmax = fmaxf(vmax, __shfl_xor(vmax, 16));
    vmax = fmaxf(vmax, __shfl_xor(vmax, 32));
    // defer-rescale: only pay alpha/exp2/O-rescale when some lane's max grew
    if (__any(vmax > mrun)) {
      float nm = fmaxf(mrun, vmax);
      float alpha = exp2f(mrun - nm);   // lanes w/o growth: exp2(0)=1
      mrun = nm;
      lrun *= alpha;
#pragma unroll
      for (int mi2 = 0; mi2 < 4; ++mi2) {
        o[mi2][0] *= alpha; o[mi2][1] *= alpha;
        o[mi2][2] *= alpha; o[mi2][3] *= alpha;
      }
    }
    float psum = 0.f;
#pragma unroll
    for (int mi = 0; mi < 4; ++mi)
#pragma unroll
      for (int r = 0; r < 4; ++r) {
        float p = exp2f(sm[mi][r] - mrun);
        sm[mi][r] = p;
        psum += p;
      }
    psum += __shfl_xor(psum, 16);
    psum += __shfl_xor(psum, 32);
    lrun += psum;

    // P^T -> LDS (q, t_k): cvt_pk packed b64, per-wave rows, no barrier needed
#pragma unroll
    for (int mi = 0; mi < 4; ++mi) {
      uint2 pk;
      pk.x = cvtpk_bf16(sm[mi][0], sm[mi][1]);
      pk.y = cvtpk_bf16(sm[mi][2], sm[mi][3]);
      *(uint2*)(Ps + (wq + ln) * 64 + ((mi * 16 + quad * 4) ^ swz)) = pk;
    }
    // O^T += V^T·P : A=Vt-frag A[m=d][k=t_k], B=P-frag B[n=q][k=t_k]
#pragma unroll
    for (int ks = 0; ks < 2; ++ks) {
      bf16x8 pb = *(const bf16x8*)(Ps + (wq + ln) * 64 + ((ks * 32 + quad * 8) ^ swz));
#pragma unroll
      for (int mi2 = 0; mi2 < 4; ++mi2) {
        bf16x8 vf = *(const bf16x8*)(Vs[cur] + (mi2 * 16 + ln) * 64 + ((ks * 32 + quad * 8) ^ swz));
        o[mi2] = __builtin_amdgcn_mfma_f32_16x16x32_bf16(vf, pb, o[mi2], 0, 0, 0);
      }
    }

    // stage next tile into the other buffer; visible after the single barrier.
    // Safe: all waves' reads of buf[cur^1] finished before the PREVIOUS barrier.
    if (kt < 31) {
      *(uint4*)(Ks[cur ^ 1] + sdst) = kpre;
      *(uint4*)(Vs[cur ^ 1] + sdst) = vpre;
      __syncthreads();
    }
  }

  // epilogue: O^T lane owns q-col (1/l per-lane), 4 consecutive d per store
  {
    float inv = 1.f / lrun;
    int t = q0 + wq + ln;
    size_t base = ((size_t)b * 2048 + t) * 512 + h * 64;
#pragma unroll
    for (int mi2 = 0; mi2 < 4; ++mi2) {
      uint2 pk;
      pk.x = cvtpk_bf16(o[mi2][0] * inv, o[mi2][1] * inv);
      pk.y = cvtpk_bf16(o[mi2][2] * inv, o[mi2][3] * inv);
      *(uint2*)(attnb + base + mi2 * 16 + quad * 4) = pk;
    }
  }
}

// ---------------------------------------------------------------------------
// proj GEMM: attnb(8192x512) @ wpb(512x512)^T + bias -> out fp32
// 64x64 tile, 256 threads (4 waves x 32x32), 2-phase dbuf pipeline.
// Grid (128,8) = 1024 blocks -> 4 blocks/CU -> 16 waves/CU.
// ---------------------------------------------------------------------------
__global__ __launch_bounds__(256) void proj_kernel(
    const unsigned short* __restrict__ ab, const unsigned short* __restrict__ wpb,
    const float* __restrict__ proj_b, float* __restrict__ out) {
  __shared__ __align__(16) unsigned short As[2][64 * 32];
  __shared__ __align__(16) unsigned short Bs[2][64 * 32];
  const int tid = threadIdx.x;
  const int wave = tid >> 6, lane = tid & 63, ln = lane & 15, quad = lane >> 4;
  const int m0 = blockIdx.x * 64, n0 = blockIdx.y * 64;
  const int wr = (wave >> 1) * 32, wc = (wave & 1) * 32;

  floatx4 acc[2][2];
#pragma unroll
  for (int i = 0; i < 2; ++i)
#pragma unroll
    for (int j = 0; j < 2; ++j) acc[i][j] = (floatx4){0.f, 0.f, 0.f, 0.f};

  // 256 threads stage 256 x 16B chunks: one A chunk + one B chunk each
  const int ar = tid >> 2, ak = (tid & 3) * 8;

  gld_lds16(As[0] + tid * 8, ab + (size_t)(m0 + ar) * 512 + ak);
  gld_lds16(Bs[0] + tid * 8, wpb + (size_t)(n0 + ar) * 512 + ak);
  __syncthreads();

  for (int kt = 0; kt < 16; ++kt) {
    const int cur = kt & 1;
    if (kt < 15) {
      const int kn = (kt + 1) * 32;
      gld_lds16(As[cur ^ 1] + tid * 8, ab + (size_t)(m0 + ar) * 512 + kn + ak);
      gld_lds16(Bs[cur ^ 1] + tid * 8, wpb + (size_t)(n0 + ar) * 512 + kn + ak);
    }
    bf16x8 af[2], bfb[2];
#pragma unroll
    for (int mi = 0; mi < 2; ++mi)
      af[mi] = *(const bf16x8*)(As[cur] + (wr + mi * 16 + ln) * 32 + quad * 8);
#pragma unroll
    for (int ni = 0; ni < 2; ++ni)
      bfb[ni] = *(const bf16x8*)(Bs[cur] + (wc + ni * 16 + ln) * 32 + quad * 8);
#pragma unroll
    for (int mi = 0; mi < 2; ++mi)
#pragma unroll
      for (int ni = 0; ni < 2; ++ni)
        acc[mi][ni] = __builtin_amdgcn_mfma_f32_16x16x32_bf16(af[mi], bfb[ni], acc[mi][ni], 0, 0, 0);
    __syncthreads();
  }

#pragma unroll
  for (int mi = 0; mi < 2; ++mi)
#pragma unroll
    for (int ni = 0; ni < 2; ++ni) {
      int col = n0 + wc + ni * 16 + ln;
      float pb = proj_b[col];
#pragma unroll
      for (int r = 0; r < 4; ++r) {
        int row = m0 + wr + mi * 16 + quad * 4 + r;
        out[(size_t)row * 512 + col] = acc[mi][ni][r] + pb;
      }
    }
}

// ---------------------------------------------------------------------------
extern "C" void kernel_launch(void* const* d_in, const int* in_sizes, int n_in,
                              void* d_out, int out_size, void* d_ws, size_t ws_size,
                              hipStream_t stream) {
  const float* x      = (const float*)d_in[0];
  const float* mask   = (const float*)d_in[1];
  const float* qkv_w  = (const float*)d_in[2];
  const float* qkv_b  = (const float*)d_in[3];
  const float* proj_w = (const float*)d_in[4];
  const float* proj_b = (const float*)d_in[5];
  float* out = (float*)d_out;

  char* ws = (char*)d_ws;
  unsigned short* xb   = (unsigned short*)(ws);
  unsigned short* wqb  = (unsigned short*)(ws + 8388608);
  unsigned short* wpb  = (unsigned short*)(ws + 9961472);
  float* cosT          = (float*)(ws + 10485760);
  float* sinT          = (float*)(ws + 10747904);
  unsigned short* Qb   = (unsigned short*)(ws + 11010048);
  unsigned short* Kb   = (unsigned short*)(ws + 19398656);
  unsigned short* Vtb  = (unsigned short*)(ws + 27787264);
  unsigned short* attnb= (unsigned short*)(ws + 36175872);

  prep_kernel<<<2816, 256, 0, stream>>>(x, qkv_w, proj_w, xb, wqb, wpb, cosT, sinT);
  dim3 g1(64, 12);
  qkv_kernel<<<g1, 256, 0, stream>>>(xb, wqb, qkv_b, cosT, sinT, Qb, Kb, Vtb);
  dim3 g2(16, 32);
  attn_kernel<<<g2, 512, 0, stream>>>(Qb, Kb, Vtb, mask, attnb);
  dim3 g3(128, 8);
  proj_kernel<<<g3, 256, 0, stream>>>(attnb, wpb, proj_b, out);
}

// Round 11
// 180.307 us; speedup vs baseline: 1.0581x; 1.0153x over previous
//
#include <hip/hip_runtime.h>
#include <math.h>

// ---------------------------------------------------------------------------
// HROMAttention: x(4,2048,512) -> QKV(+bias) -> RoPE -> MHA(8 heads, d=64)
//                -> proj(+bias). All GEMMs bf16 MFMA 16x16x32, fp32 accum.
// Round 12: qkv occupancy fix (only change vs R11/183.1us best):
//   qkv: 128x128 tile, 512 threads / 8 waves (each 32x64, acc[2][4]) ->
//        grid (64,12)=768 blocks stays, but 24 (or 16) waves/CU vs 12.
//        Staging = 1 A + 1 B 16B chunk per thread (proj pattern).
//        Epilogues re-derived for the 4x2 wave grid.
//   attn: exact R5/R11 (82.4 us measured optimum, 6 variants all lost).
//   proj: R8 64x64 tiles. prep: R5.
// ws layout (bytes):
//   [0)         xb     bf16 8192x512     8388608
//   [8388608)   wqb    bf16 1536x512     1572864
//   [9961472)   wpb    bf16  512x512      524288
//   [10485760)  cosT   f32  2048x32       262144
//   [10747904)  sinT   f32  2048x32       262144
//   [11010048)  Qb     bf16 (b,h,t,d)    8388608   (pre-scaled by 0.125*log2e)
//   [19398656)  Kb     bf16 (b,h,t,d)    8388608
//   [27787264)  Vtb    bf16 (b,h,d,t)    8388608
//   [36175872)  attnb  bf16 8192x512     8388608
// total 44564480 B (~42.5 MB) of d_ws
// ---------------------------------------------------------------------------

typedef __attribute__((ext_vector_type(8))) short bf16x8;
typedef __attribute__((ext_vector_type(4))) float floatx4;

#define LOG2E 1.44269504088896f

__device__ __forceinline__ unsigned short f2bf(float f) {
  unsigned int u = __float_as_uint(f);
  u += 0x7fffu + ((u >> 16) & 1u);   // round-to-nearest-even
  return (unsigned short)(u >> 16);
}

// pack two f32 -> bf16x2 (low16 = a, high16 = b), RNE, single VALU inst
__device__ __forceinline__ unsigned int cvtpk_bf16(float a, float b) {
  unsigned int r;
  asm("v_cvt_pk_bf16_f32 %0, %1, %2" : "=v"(r) : "v"(a), "v"(b));
  return r;
}

__device__ __forceinline__ void gld_lds16(unsigned short* lds, const unsigned short* g) {
  __builtin_amdgcn_global_load_lds(
      (const __attribute__((address_space(1))) unsigned int*)g,
      (__attribute__((address_space(3))) unsigned int*)lds, 16, 0, 0);
}

// ---------------------------------------------------------------------------
// prep: bf16 conversions (8 elems/thread) + RoPE cos/sin table (fp64 trig)
// f32 elements: x 4194304 | wq 786432 | wp 262144  (all /8) -> 655360 threads
// table: 65536 entries, 1/thread -> threads 655360..720895
// ---------------------------------------------------------------------------
__global__ __launch_bounds__(256) void prep_kernel(
    const float* __restrict__ x, const float* __restrict__ wq, const float* __restrict__ wp,
    unsigned short* __restrict__ xb, unsigned short* __restrict__ wqb,
    unsigned short* __restrict__ wpb, float* __restrict__ cosT, float* __restrict__ sinT) {
  int i = blockIdx.x * 256 + threadIdx.x;
  if (i < 655360) {
    int base = i * 8;
    const float* src;
    unsigned short* dst;
    int j;
    if (base < 4194304)      { src = x;  dst = xb;  j = base; }
    else if (base < 4980736) { src = wq; dst = wqb; j = base - 4194304; }
    else                     { src = wp; dst = wpb; j = base - 4980736; }
    float4 a = *(const float4*)(src + j);
    float4 b = *(const float4*)(src + j + 4);
    uint4 r;
    r.x = cvtpk_bf16(a.x, a.y);
    r.y = cvtpk_bf16(a.z, a.w);
    r.z = cvtpk_bf16(b.x, b.y);
    r.w = cvtpk_bf16(b.z, b.w);
    *(uint4*)(dst + j) = r;
  } else if (i < 720896) {
    int j = i - 655360;
    int t = j >> 5, f = j & 31;
    double fr = (double)t * pow(10000.0, -(double)f / 32.0);
    cosT[j] = (float)cos(fr);
    sinT[j] = (float)sin(fr);
  }
}

// ---------------------------------------------------------------------------
// QKV GEMM: xb(8192x512) @ wqb(1536x512)^T + bias, epilogue RoPE + scatter
// 128x128 tile, BK=32, 512 threads / 8 waves (4x2 grid, 32x64 per wave).
// 2-phase dbuf pipeline; epilogues re-tile through the dead 32 KB GEMM LDS
// for coalesced 16B stores.
// ---------------------------------------------------------------------------
__global__ __launch_bounds__(512) void qkv_kernel(
    const unsigned short* __restrict__ xb, const unsigned short* __restrict__ wqb,
    const float* __restrict__ qkv_b, const float* __restrict__ cosT,
    const float* __restrict__ sinT, unsigned short* __restrict__ Qb,
    unsigned short* __restrict__ Kb, unsigned short* __restrict__ Vtb) {
  // [buf][A=0/B=1][128*32] ; whole 32 KB reused as epilogue transpose buffer
  __shared__ __align__(16) unsigned short SM[2][2][128 * 32];
  const int tid = threadIdx.x;
  const int wave = tid >> 6, lane = tid & 63, ln = lane & 15, quad = lane >> 4;
  const int m0 = blockIdx.x * 128, n0 = blockIdx.y * 128;
  const int wr = (wave >> 1) * 32, wc = (wave & 1) * 64;

  floatx4 acc[2][4];
#pragma unroll
  for (int i = 0; i < 2; ++i)
#pragma unroll
    for (int j = 0; j < 4; ++j) acc[i][j] = (floatx4){0.f, 0.f, 0.f, 0.f};

  // 512 threads stage 512 x 16B chunks of each 128x32 tile (1 A + 1 B each)
  const int ar = tid >> 2, ak = (tid & 3) * 8;

  // prologue: stage K-tile 0 into buffer 0
  gld_lds16(SM[0][0] + tid * 8, xb + (size_t)(m0 + ar) * 512 + ak);
  gld_lds16(SM[0][1] + tid * 8, wqb + (size_t)(n0 + ar) * 512 + ak);
  __syncthreads();

  for (int kt = 0; kt < 16; ++kt) {
    const int cur = kt & 1;
    if (kt < 15) {
      const int kn = (kt + 1) * 32;
      gld_lds16(SM[cur ^ 1][0] + tid * 8, xb + (size_t)(m0 + ar) * 512 + kn + ak);
      gld_lds16(SM[cur ^ 1][1] + tid * 8, wqb + (size_t)(n0 + ar) * 512 + kn + ak);
    }
    bf16x8 af[2], bfb[4];
#pragma unroll
    for (int mi = 0; mi < 2; ++mi)
      af[mi] = *(const bf16x8*)(SM[cur][0] + (wr + mi * 16 + ln) * 32 + quad * 8);
#pragma unroll
    for (int ni = 0; ni < 4; ++ni)
      bfb[ni] = *(const bf16x8*)(SM[cur][1] + (wc + ni * 16 + ln) * 32 + quad * 8);
#pragma unroll
    for (int mi = 0; mi < 2; ++mi)
#pragma unroll
      for (int ni = 0; ni < 4; ++ni)
        acc[mi][ni] = __builtin_amdgcn_mfma_f32_16x16x32_bf16(af[mi], bfb[ni], acc[mi][ni], 0, 0, 0);
    __syncthreads();
  }

  // epilogue: mat is block-uniform (512 % 128 == 0); wave's 64 cols (wc) lie
  // in exactly one (mat, head) since wc in {0,64}.
  const int colbase = n0 + wc;                    // multiple of 64
  const int mat = colbase >> 9;                   // 0=q 1=k 2=v
  float bias[4];
#pragma unroll
  for (int ni = 0; ni < 4; ++ni) bias[ni] = qkv_b[colbase + ni * 16 + ln];

  unsigned short* Ls = &SM[0][0][0];              // 32 KB scratch, GEMM tiles dead
  const int bidx = m0 >> 11, tl0 = m0 & 2047;     // block spans one batch
  const int h0 = (n0 & 511) >> 6;                 // first head in block

  if (mat == 2) {
    // V: Ls[c][r], c = local col (head*64+d), r = local t; phys granule swizzle
#pragma unroll
    for (int mi = 0; mi < 2; ++mi) {
      int r0 = wr + mi * 16 + quad * 4;            // 4 consecutive t
#pragma unroll
      for (int ni = 0; ni < 4; ++ni) {
        int c = wc + ni * 16 + ln;
        ushort4 pk;
        pk.x = f2bf(acc[mi][ni][0] + bias[ni]);
        pk.y = f2bf(acc[mi][ni][1] + bias[ni]);
        pk.z = f2bf(acc[mi][ni][2] + bias[ni]);
        pk.w = f2bf(acc[mi][ni][3] + bias[ni]);
        *(ushort4*)(Ls + c * 128 + (r0 ^ ((c & 7) << 3))) = pk;
      }
    }
    __syncthreads();
    // store: lanes cover t-contiguous 16B chunks of one (bh,d) row
    const int j2 = tid & 15, rid = tid >> 4;       // rid 0..31
#pragma unroll
    for (int it = 0; it < 4; ++it) {
      int c = it * 32 + rid;                       // 0..127
      int hh = c >> 6, dd = c & 63;
      uint4 v = *(const uint4*)(Ls + c * 128 + ((j2 * 8) ^ ((c & 7) << 3)));
      *(uint4*)(Vtb + ((size_t)(bidx * 8 + h0 + hh) * 64 + dd) * 2048 + tl0 + j2 * 8) = v;
    }
  } else {
    // Q/K: RoPE in-register -> Ls[r][c] (r = local t, c = local col), then
    // coalesced 16B stores along d.
    unsigned short* dst = (mat == 0) ? Qb : Kb;
    const float sc = (mat == 0) ? 0.125f * LOG2E : 1.0f;
#pragma unroll
    for (int mi = 0; mi < 2; ++mi) {
#pragma unroll
      for (int r = 0; r < 4; ++r) {
        int lr = wr + mi * 16 + quad * 4 + r;      // local t 0..127
        int t = tl0 + lr;
        const float* cr = cosT + t * 32;
        const float* sr = sinT + t * 32;
        int xr = (lr & 7) << 3;
#pragma unroll
        for (int ni = 0; ni < 2; ++ni) {
          int dlo = ni * 16 + ln;                  // 0..31 within head
          float cv = cr[dlo], sv = sr[dlo];
          float xlo = acc[mi][ni][r] + bias[ni];
          float xhi = acc[mi][ni + 2][r] + bias[ni + 2];
          Ls[lr * 128 + ((wc + dlo) ^ xr)]      = f2bf((xlo * cv - xhi * sv) * sc);
          Ls[lr * 128 + ((wc + dlo + 32) ^ xr)] = f2bf((xhi * cv + xlo * sv) * sc);
        }
      }
    }
    __syncthreads();
    // store: 8 lanes cover one 128B (bh,t) row; 64 rows per pass, 4 passes
    const int jj = tid & 7, rowid = tid >> 3;      // jj = 16B chunk, rowid 0..63
#pragma unroll
    for (int it = 0; it < 4; ++it) {
      int hr = it * 64 + rowid;                    // 0..255 head-rows
      int rr = hr & 127, hh = hr >> 7;
      int c = hh * 64 + jj * 8;
      uint4 v = *(const uint4*)(Ls + rr * 128 + (c ^ ((rr & 7) << 3)));
      *(uint4*)(dst + ((size_t)(bidx * 8 + h0 + hh) * 2048 + tl0 + rr) * 64 + jj * 8) = v;
    }
  }
}

// ---------------------------------------------------------------------------
// Transposed flash attention (exact R5 structure, 82.4 us measured best):
//   block = 128 q x one (b,h); 8 waves x 16 q each; K-tile = 64.
//   S^T = K·Q^T; XOR-swizzled LDS; cvt_pk P-pack; defer-rescale.
//   Loop: prefetch regs(t+1) -> compute from buf[cur] -> write buf[cur^1]
//   -> ONE barrier per tile.
// ---------------------------------------------------------------------------
__global__ __launch_bounds__(512) void attn_kernel(
    const unsigned short* __restrict__ Qb, const unsigned short* __restrict__ Kb,
    const unsigned short* __restrict__ Vtb, const float* __restrict__ mask,
    unsigned short* __restrict__ attnb) {
  __shared__ __align__(16) unsigned short Ks[2][64 * 64];  // (t_k, d) swizzled
  __shared__ __align__(16) unsigned short Vs[2][64 * 64];  // (d, t_k) swizzled
  __shared__ __align__(16) unsigned short Ps[128 * 64];    // (q, t_k) swizzled

  const int tid = threadIdx.x;
  const int wave = tid >> 6, lane = tid & 63, ln = lane & 15, quad = lane >> 4;
  const int swz = (ln & 7) << 3;                 // row-derived XOR for frag reads
  const int bh = blockIdx.y;
  const int b = bh >> 3, h = bh & 7;
  const int q0 = blockIdx.x * 128;
  const int wq = wave * 16;                      // wave's local q base

  const unsigned short* Qhead = Qb + (size_t)bh * 2048 * 64;
  const unsigned short* Khead = Kb + (size_t)bh * 2048 * 64;
  const unsigned short* Vhead = Vtb + (size_t)bh * 64 * 2048;

  bf16x8 qf[2];
#pragma unroll
  for (int ks = 0; ks < 2; ++ks)
    qf[ks] = *(const bf16x8*)(Qhead + (size_t)(q0 + wq + ln) * 64 + ks * 32 + quad * 8);

  floatx4 o[4];   // O^T: [d-tile], lane col = q
#pragma unroll
  for (int mi2 = 0; mi2 < 4; ++mi2) o[mi2] = (floatx4){0.f, 0.f, 0.f, 0.f};
  float mrun = -INFINITY;
  float lrun = 0.f;

  const int srow = tid >> 3;                     // 0..63
  const int scol = (tid & 7) * 8;                // shorts
  const int sdst = srow * 64 + (scol ^ ((srow & 7) << 3));

  // prologue: tile 0 -> regs -> buf 0
  {
    uint4 k0v = *(const uint4*)(Khead + (size_t)srow * 64 + scol);
    uint4 v0v = *(const uint4*)(Vhead + (size_t)srow * 2048 + scol);
    *(uint4*)(Ks[0] + sdst) = k0v;
    *(uint4*)(Vs[0] + sdst) = v0v;
  }
  __syncthreads();

  for (int kt = 0; kt < 32; ++kt) {
    const int cur = kt & 1;
    const int k0 = kt * 64;
    uint4 kpre, vpre;
    if (kt < 31) {   // prefetch next tile; latency hidden by compute below
      kpre = *(const uint4*)(Khead + (size_t)(k0 + 64 + srow) * 64 + scol);
      vpre = *(const uint4*)(Vhead + (size_t)srow * 2048 + k0 + 64 + scol);
    }

    // S^T = K·Q^T : A=K-frag A[m=t_k][k=d], B=Q. C: row=t_k(quad*4+r), col=q(ln)
    floatx4 sm[4];
#pragma unroll
    for (int mi = 0; mi < 4; ++mi) {
      bf16x8 kf0 = *(const bf16x8*)(Ks[cur] + (mi * 16 + ln) * 64 + ((quad * 8) ^ swz));
      bf16x8 kf1 = *(const bf16x8*)(Ks[cur] + (mi * 16 + ln) * 64 + ((32 + quad * 8) ^ swz));
      floatx4 a = (floatx4){0.f, 0.f, 0.f, 0.f};
      a = __builtin_amdgcn_mfma_f32_16x16x32_bf16(kf0, qf[0], a, 0, 0, 0);
      a = __builtin_amdgcn_mfma_f32_16x16x32_bf16(kf1, qf[1], a, 0, 0, 0);
      sm[mi] = a;
    }
#pragma unroll
    for (int mi = 0; mi < 4; ++mi) {
      float4 mv = *(const float4*)(mask + b * 2048 + k0 + mi * 16 + quad * 4);
      sm[mi][0] += mv.x * LOG2E; sm[mi][1] += mv.y * LOG2E;
      sm[mi][2] += mv.z * LOG2E; sm[mi][3] += mv.w * LOG2E;
    }
    // online softmax: per lane one q-column -> 15 in-reg max + 2 shuffles
    float vmax = fmaxf(fmaxf(sm[0][0], sm[0][1]), fmaxf(sm[0][2], sm[0][3]));
#pragma unroll
    for (int mi = 1; mi < 4; ++mi)
      vmax = fmaxf(vmax, fmaxf(fmaxf(sm[mi][0], sm[mi][1]), fmaxf(sm[mi][2], sm[mi][3])));
    vmax = fmaxf(vmax, __shfl_xor(vmax, 16));
    vmax = fmaxf(vmax, __shfl_xor(vmax, 32));
    // defer-rescale: only pay alpha/exp2/O-rescale when some lane's max grew
    if (__any(vmax > mrun)) {
      float nm = fmaxf(mrun, vmax);
      float alpha = exp2f(mrun - nm);   // lanes w/o growth: exp2(0)=1
      mrun = nm;
      lrun *= alpha;
#pragma unroll
      for (int mi2 = 0; mi2 < 4; ++mi2) {
        o[mi2][0] *= alpha; o[mi2][1] *= alpha;
        o[mi2][2] *= alpha; o[mi2][3] *= alpha;
      }
    }
    float psum = 0.f;
#pragma unroll
    for (int mi = 0; mi < 4; ++mi)
#pragma unroll
      for (int r = 0; r < 4; ++r) {
        float p = exp2f(sm[mi][r] - mrun);
        sm[mi][r] = p;
        psum += p;
      }
    psum += __shfl_xor(psum, 16);
    psum += __shfl_xor(psum, 32);
    lrun += psum;

    // P^T -> LDS (q, t_k): cvt_pk packed b64, per-wave rows, no barrier needed
#pragma unroll
    for (int mi = 0; mi < 4; ++mi) {
      uint2 pk;
      pk.x = cvtpk_bf16(sm[mi][0], sm[mi][1]);
      pk.y = cvtpk_bf16(sm[mi][2], sm[mi][3]);
      *(uint2*)(Ps + (wq + ln) * 64 + ((mi * 16 + quad * 4) ^ swz)) = pk;
    }
    // O^T += V^T·P : A=Vt-frag A[m=d][k=t_k], B=P-frag B[n=q][k=t_k]
#pragma unroll
    for (int ks = 0; ks < 2; ++ks) {
      bf16x8 pb = *(const bf16x8*)(Ps + (wq + ln) * 64 + ((ks * 32 + quad * 8) ^ swz));
#pragma unroll
      for (int mi2 = 0; mi2 < 4; ++mi2) {
        bf16x8 vf = *(const bf16x8*)(Vs[cur] + (mi2 * 16 + ln) * 64 + ((ks * 32 + quad * 8) ^ swz));
        o[mi2] = __builtin_amdgcn_mfma_f32_16x16x32_bf16(vf, pb, o[mi2], 0, 0, 0);
      }
    }

    // stage next tile into the other buffer; visible after the single barrier.
    // Safe: all waves' reads of buf[cur^1] finished before the PREVIOUS barrier.
    if (kt < 31) {
      *(uint4*)(Ks[cur ^ 1] + sdst) = kpre;
      *(uint4*)(Vs[cur ^ 1] + sdst) = vpre;
      __syncthreads();
    }
  }

  // epilogue: O^T lane owns q-col (1/l per-lane), 4 consecutive d per store
  {
    float inv = 1.f / lrun;
    int t = q0 + wq + ln;
    size_t base = ((size_t)b * 2048 + t) * 512 + h * 64;
#pragma unroll
    for (int mi2 = 0; mi2 < 4; ++mi2) {
      uint2 pk;
      pk.x = cvtpk_bf16(o[mi2][0] * inv, o[mi2][1] * inv);
      pk.y = cvtpk_bf16(o[mi2][2] * inv, o[mi2][3] * inv);
      *(uint2*)(attnb + base + mi2 * 16 + quad * 4) = pk;
    }
  }
}

// ---------------------------------------------------------------------------
// proj GEMM: attnb(8192x512) @ wpb(512x512)^T + bias -> out fp32
// 64x64 tile, 256 threads (4 waves x 32x32), 2-phase dbuf pipeline.
// Grid (128,8) = 1024 blocks -> 4 blocks/CU -> 16 waves/CU.
// ---------------------------------------------------------------------------
__global__ __launch_bounds__(256) void proj_kernel(
    const unsigned short* __restrict__ ab, const unsigned short* __restrict__ wpb,
    const float* __restrict__ proj_b, float* __restrict__ out) {
  __shared__ __align__(16) unsigned short As[2][64 * 32];
  __shared__ __align__(16) unsigned short Bs[2][64 * 32];
  const int tid = threadIdx.x;
  const int wave = tid >> 6, lane = tid & 63, ln = lane & 15, quad = lane >> 4;
  const int m0 = blockIdx.x * 64, n0 = blockIdx.y * 64;
  const int wr = (wave >> 1) * 32, wc = (wave & 1) * 32;

  floatx4 acc[2][2];
#pragma unroll
  for (int i = 0; i < 2; ++i)
#pragma unroll
    for (int j = 0; j < 2; ++j) acc[i][j] = (floatx4){0.f, 0.f, 0.f, 0.f};

  // 256 threads stage 256 x 16B chunks: one A chunk + one B chunk each
  const int ar = tid >> 2, ak = (tid & 3) * 8;

  gld_lds16(As[0] + tid * 8, ab + (size_t)(m0 + ar) * 512 + ak);
  gld_lds16(Bs[0] + tid * 8, wpb + (size_t)(n0 + ar) * 512 + ak);
  __syncthreads();

  for (int kt = 0; kt < 16; ++kt) {
    const int cur = kt & 1;
    if (kt < 15) {
      const int kn = (kt + 1) * 32;
      gld_lds16(As[cur ^ 1] + tid * 8, ab + (size_t)(m0 + ar) * 512 + kn + ak);
      gld_lds16(Bs[cur ^ 1] + tid * 8, wpb + (size_t)(n0 + ar) * 512 + kn + ak);
    }
    bf16x8 af[2], bfb[2];
#pragma unroll
    for (int mi = 0; mi < 2; ++mi)
      af[mi] = *(const bf16x8*)(As[cur] + (wr + mi * 16 + ln) * 32 + quad * 8);
#pragma unroll
    for (int ni = 0; ni < 2; ++ni)
      bfb[ni] = *(const bf16x8*)(Bs[cur] + (wc + ni * 16 + ln) * 32 + quad * 8);
#pragma unroll
    for (int mi = 0; mi < 2; ++mi)
#pragma unroll
      for (int ni = 0; ni < 2; ++ni)
        acc[mi][ni] = __builtin_amdgcn_mfma_f32_16x16x32_bf16(af[mi], bfb[ni], acc[mi][ni], 0, 0, 0);
    __syncthreads();
  }

#pragma unroll
  for (int mi = 0; mi < 2; ++mi)
#pragma unroll
    for (int ni = 0; ni < 2; ++ni) {
      int col = n0 + wc + ni * 16 + ln;
      float pb = proj_b[col];
#pragma unroll
      for (int r = 0; r < 4; ++r) {
        int row = m0 + wr + mi * 16 + quad * 4 + r;
        out[(size_t)row * 512 + col] = acc[mi][ni][r] + pb;
      }
    }
}

// ---------------------------------------------------------------------------
extern "C" void kernel_launch(void* const* d_in, const int* in_sizes, int n_in,
                              void* d_out, int out_size, void* d_ws, size_t ws_size,
                              hipStream_t stream) {
  const float* x      = (const float*)d_in[0];
  const float* mask   = (const float*)d_in[1];
  const float* qkv_w  = (const float*)d_in[2];
  const float* qkv_b  = (const float*)d_in[3];
  const float* proj_w = (const float*)d_in[4];
  const float* proj_b = (const float*)d_in[5];
  float* out = (float*)d_out;

  char* ws = (char*)d_ws;
  unsigned short* xb   = (unsigned short*)(ws);
  unsigned short* wqb  = (unsigned short*)(ws + 8388608);
  unsigned short* wpb  = (unsigned short*)(ws + 9961472);
  float* cosT          = (float*)(ws + 10485760);
  float* sinT          = (float*)(ws + 10747904);
  unsigned short* Qb   = (unsigned short*)(ws + 11010048);
  unsigned short* Kb   = (unsigned short*)(ws + 19398656);
  unsigned short* Vtb  = (unsigned short*)(ws + 27787264);
  unsigned short* attnb= (unsigned short*)(ws + 36175872);

  prep_kernel<<<2816, 256, 0, stream>>>(x, qkv_w, proj_w, xb, wqb, wpb, cosT, sinT);
  dim3 g1(64, 12);
  qkv_kernel<<<g1, 512, 0, stream>>>(xb, wqb, qkv_b, cosT, sinT, Qb, Kb, Vtb);
  dim3 g2(16, 32);
  attn_kernel<<<g2, 512, 0, stream>>>(Qb, Kb, Vtb, mask, attnb);
  dim3 g3(128, 8);
  proj_kernel<<<g3, 256, 0, stream>>>(attnb, wpb, proj_b, out);
}